// Round 1
// baseline (85.666 us; speedup 1.0000x reference)
//
#include <hip/hip_runtime.h>

// NT-Xent loss, B=4096, D=256, N=8192, T=0.5
// loss = [ sum_r ( log(sum_{c!=r} exp(2*f_r.f_c)) - 2*f_r.f_pos(r) ) ] / N^2

#define B_ROWS 4096
#define DIM 256
#define NTOT 8192
#define NCHUNK 16
#define CHUNK_COLS 512   // NTOT / NCHUNK
#define BLK_ROWS 512     // rows per block in k_simsum (8 waves * 64)
#define WAVE_ROWS 64

typedef __bf16 bf16x8 __attribute__((ext_vector_type(8)));
typedef unsigned short u16x8 __attribute__((ext_vector_type(8)));
typedef float f32x4 __attribute__((ext_vector_type(4)));

__device__ __forceinline__ unsigned short f2bf(float x) {
    unsigned int u = __builtin_bit_cast(unsigned int, x);
    u += 0x7fffu + ((u >> 16) & 1u);   // RTNE
    return (unsigned short)(u >> 16);
}

__device__ __forceinline__ float wave_reduce_add(float v) {
#pragma unroll
    for (int m = 1; m < 64; m <<= 1) v += __shfl_xor(v, m, 64);
    return v;
}

// K1: one wave per row-pair (r, r+B). Normalize both rows (fp32), write bf16
// feats, and compute the positive-pair sim (fp32, exact vs reference).
__global__ __launch_bounds__(64) void k_norm(const float* __restrict__ zi,
                                             const float* __restrict__ zj,
                                             unsigned short* __restrict__ F,
                                             float* __restrict__ pos_sim) {
    const int r = blockIdx.x;
    const int lane = threadIdx.x;
    const float4 vi = reinterpret_cast<const float4*>(zi + (size_t)r * DIM)[lane];
    const float4 vj = reinterpret_cast<const float4*>(zj + (size_t)r * DIM)[lane];
    float si = vi.x * vi.x + vi.y * vi.y + vi.z * vi.z + vi.w * vi.w;
    float sj = vj.x * vj.x + vj.y * vj.y + vj.z * vj.z + vj.w * vj.w;
    si = wave_reduce_add(si);
    sj = wave_reduce_add(sj);
    const float ri = 1.0f / sqrtf(si);
    const float rj = 1.0f / sqrtf(sj);
    const float a0 = vi.x * ri, a1 = vi.y * ri, a2 = vi.z * ri, a3 = vi.w * ri;
    const float b0 = vj.x * rj, b1 = vj.y * rj, b2 = vj.z * rj, b3 = vj.w * rj;
    float dot = a0 * b0 + a1 * b1 + a2 * b2 + a3 * b3;
    dot = wave_reduce_add(dot);
    ushort4 oa = make_ushort4(f2bf(a0), f2bf(a1), f2bf(a2), f2bf(a3));
    ushort4 ob = make_ushort4(f2bf(b0), f2bf(b1), f2bf(b2), f2bf(b3));
    reinterpret_cast<ushort4*>(F + (size_t)r * DIM)[lane] = oa;
    reinterpret_cast<ushort4*>(F + (size_t)(r + B_ROWS) * DIM)[lane] = ob;
    if (lane == 0) {
        const float ps = 2.0f * dot;     // sim = dot / 0.5
        pos_sim[r] = ps;
        pos_sim[r + B_ROWS] = ps;
    }
}

// K2: fused sim-GEMM + exp row-sum. Block = 8 waves (512 thr), each wave owns
// 64 rows with its A-operand fully in registers (no LDS, no barriers).
// Streams 512 columns (its chunk) in 32-col tiles; B frags from global (L2/L1).
__global__ __launch_bounds__(512, 2) void k_simsum(const unsigned short* __restrict__ Fu,
                                                   float* __restrict__ Spart) {
    const int bid = blockIdx.x;
    const int rt = bid >> 4;   // 16 row tiles of 512 rows
    const int ch = bid & 15;   // 16 column chunks of 512 cols
    const int tid = threadIdx.x;
    const int wave = tid >> 6;
    const int lane = tid & 63;
    const int m16 = lane & 15;
    const int g4 = lane >> 4;

    const int row0 = rt * BLK_ROWS + wave * WAVE_ROWS;
    const int col0 = ch * CHUNK_COLS;

    // A fragments: 4 row-frags (16 rows each) x 8 k-steps (K=32 each) = 128 VGPRs
    bf16x8 a[4][8];
#pragma unroll
    for (int rf = 0; rf < 4; ++rf) {
        const unsigned short* rp = Fu + (size_t)(row0 + rf * 16 + m16) * DIM + g4 * 8;
#pragma unroll
        for (int ks = 0; ks < 8; ++ks) {
            a[rf][ks] = __builtin_bit_cast(bf16x8, *reinterpret_cast<const u16x8*>(rp + ks * 32));
        }
    }

    float sums[4][4];
#pragma unroll
    for (int i = 0; i < 4; ++i)
#pragma unroll
        for (int j = 0; j < 4; ++j) sums[i][j] = 0.0f;

    for (int it = 0; it < CHUNK_COLS / 32; ++it) {
        const int cb = col0 + it * 32;
        f32x4 acc[4][2];
#pragma unroll
        for (int rf = 0; rf < 4; ++rf)
#pragma unroll
            for (int cf = 0; cf < 2; ++cf) acc[rf][cf] = f32x4{0.f, 0.f, 0.f, 0.f};

#pragma unroll
        for (int ks = 0; ks < 8; ++ks) {
            const unsigned short* bp0 = Fu + (size_t)(cb + m16) * DIM + ks * 32 + g4 * 8;
            const bf16x8 b0 = __builtin_bit_cast(bf16x8, *reinterpret_cast<const u16x8*>(bp0));
            const bf16x8 b1 = __builtin_bit_cast(bf16x8, *reinterpret_cast<const u16x8*>(bp0 + 16 * DIM));
#pragma unroll
            for (int rf = 0; rf < 4; ++rf) {
                acc[rf][0] = __builtin_amdgcn_mfma_f32_16x16x32_bf16(a[rf][ks], b0, acc[rf][0], 0, 0, 0);
                acc[rf][1] = __builtin_amdgcn_mfma_f32_16x16x32_bf16(a[rf][ks], b1, acc[rf][1], 0, 0, 0);
            }
        }

        // epilogue: sim=2*dot, exp, mask diagonal, accumulate per-row sums
#pragma unroll
        for (int rf = 0; rf < 4; ++rf) {
            const int rbase = row0 + rf * 16 + g4 * 4;
#pragma unroll
            for (int cf = 0; cf < 2; ++cf) {
                const int gcol = cb + cf * 16 + m16;
#pragma unroll
                for (int j = 0; j < 4; ++j) {
                    const float e = __expf(2.0f * acc[rf][cf][j]);
                    sums[rf][j] += (rbase + j == gcol) ? 0.0f : e;
                }
            }
        }
    }

    // reduce each row's partial across the 16 lanes holding its columns
#pragma unroll
    for (int rf = 0; rf < 4; ++rf) {
#pragma unroll
        for (int j = 0; j < 4; ++j) {
            float s = sums[rf][j];
            s += __shfl_xor(s, 1, 64);
            s += __shfl_xor(s, 2, 64);
            s += __shfl_xor(s, 4, 64);
            s += __shfl_xor(s, 8, 64);
            if (m16 == 0) {
                Spart[(size_t)ch * NTOT + (row0 + rf * 16 + g4 * 4 + j)] = s;
            }
        }
    }
}

// K3: combine chunk partials, nll = log(S) - pos_sim, reduce, /N^2
__global__ __launch_bounds__(1024) void k_final(const float* __restrict__ Spart,
                                                const float* __restrict__ pos_sim,
                                                float* __restrict__ out) {
    __shared__ float red[16];
    const int tid = threadIdx.x;
    float local = 0.0f;
    for (int r = tid; r < NTOT; r += 1024) {
        float s = 0.0f;
#pragma unroll
        for (int c = 0; c < NCHUNK; ++c) s += Spart[c * NTOT + r];
        local += logf(s) - pos_sim[r];
    }
    local = wave_reduce_add(local);
    const int wv = tid >> 6;
    if ((tid & 63) == 0) red[wv] = local;
    __syncthreads();
    if (tid == 0) {
        float tot = 0.0f;
#pragma unroll
        for (int w = 0; w < 16; ++w) tot += red[w];
        out[0] = tot / ((float)NTOT * (float)NTOT);
    }
}

extern "C" void kernel_launch(void* const* d_in, const int* in_sizes, int n_in,
                              void* d_out, int out_size, void* d_ws, size_t ws_size,
                              hipStream_t stream) {
    (void)in_sizes; (void)n_in; (void)out_size; (void)ws_size;
    const float* zi = (const float*)d_in[0];
    const float* zj = (const float*)d_in[1];
    float* out = (float*)d_out;

    char* ws = (char*)d_ws;
    unsigned short* F = (unsigned short*)ws;                               // 4 MiB bf16 feats
    float* pos_sim = (float*)(ws + (size_t)NTOT * DIM * 2);                // 32 KiB
    float* Spart = (float*)(ws + (size_t)NTOT * DIM * 2 + 65536);          // 512 KiB

    k_norm<<<B_ROWS, 64, 0, stream>>>(zi, zj, F, pos_sim);
    k_simsum<<<256, 512, 0, stream>>>(F, Spart);
    k_final<<<1, 1024, 0, stream>>>(Spart, pos_sim, out);
}

// Round 2
// 56.509 us; speedup vs baseline: 1.5160x; 1.5160x over previous
//
#include <hip/hip_runtime.h>

// NT-Xent loss, B=4096, D=256, N=8192, T=0.5
// loss = [ sum_r ( log(sum_{c!=r} exp(2*f_r.f_c)) - 2*f_r.f_pos(r) ) ] / N^2
// v2: fp8-e4m3 sim GEMM, A-resident-in-regs (64 VGPR), LDS-staged B w/ swizzle.

#define B_ROWS 4096
#define DIM 256
#define NTOT 8192
#define NCHUNK 32
#define CHUNK_COLS 256   // cols per block
#define TILE_COLS 32     // cols per inner tile
#define NTILE (CHUNK_COLS / TILE_COLS)
#define WAVES 4
#define BLK_ROWS 256     // 4 waves * 64 rows
#define WAVE_ROWS 64

typedef float f32x4 __attribute__((ext_vector_type(4)));
typedef __attribute__((address_space(1))) const unsigned int gas_uint;
typedef __attribute__((address_space(3))) unsigned int las_uint;

__device__ __forceinline__ float wave_reduce_add(float v) {
#pragma unroll
    for (int m = 1; m < 64; m <<= 1) v += __shfl_xor(v, m, 64);
    return v;
}

// K1: 4 waves/block, each wave one row-pair. Normalize (fp32), write fp8 feats,
// exact fp32 positive-pair sims.
__global__ __launch_bounds__(256) void k_norm(const float* __restrict__ zi,
                                              const float* __restrict__ zj,
                                              unsigned char* __restrict__ F8,
                                              float* __restrict__ pos_sim) {
    const int wave = threadIdx.x >> 6;
    const int lane = threadIdx.x & 63;
    const int r = blockIdx.x * WAVES + wave;
    const float4 vi = reinterpret_cast<const float4*>(zi + (size_t)r * DIM)[lane];
    const float4 vj = reinterpret_cast<const float4*>(zj + (size_t)r * DIM)[lane];
    float si = vi.x * vi.x + vi.y * vi.y + vi.z * vi.z + vi.w * vi.w;
    float sj = vj.x * vj.x + vj.y * vj.y + vj.z * vj.z + vj.w * vj.w;
    si = wave_reduce_add(si);
    sj = wave_reduce_add(sj);
    const float ri = 1.0f / sqrtf(si);
    const float rj = 1.0f / sqrtf(sj);
    const float a0 = vi.x * ri, a1 = vi.y * ri, a2 = vi.z * ri, a3 = vi.w * ri;
    const float b0 = vj.x * rj, b1 = vj.y * rj, b2 = vj.z * rj, b3 = vj.w * rj;
    float dot = a0 * b0 + a1 * b1 + a2 * b2 + a3 * b3;
    dot = wave_reduce_add(dot);
    int pa = __builtin_amdgcn_cvt_pk_fp8_f32(a0, a1, 0, false);
    pa = __builtin_amdgcn_cvt_pk_fp8_f32(a2, a3, pa, true);
    int pb = __builtin_amdgcn_cvt_pk_fp8_f32(b0, b1, 0, false);
    pb = __builtin_amdgcn_cvt_pk_fp8_f32(b2, b3, pb, true);
    reinterpret_cast<int*>(F8 + (size_t)r * DIM)[lane] = pa;
    reinterpret_cast<int*>(F8 + (size_t)(r + B_ROWS) * DIM)[lane] = pb;
    if (lane == 0) {
        const float ps = 2.0f * dot;
        pos_sim[r] = ps;
        pos_sim[r + B_ROWS] = ps;
    }
}

// K2: fp8 sim GEMM + fused exp row-sum.
// Block = 4 waves (256 thr). Wave owns 64 rows, A fully register-resident
// (32 longs = 64 VGPR). B: 32-col tile (8KB fp8) double-buffered in LDS via
// global_load_lds(16B), XOR-swizzled (o ^= (c&7)<<4) on the GLOBAL source +
// matching swizzled ds_read -> conflict-free b64 reads.
__global__ __launch_bounds__(256, 3) void k_simsum(const unsigned char* __restrict__ F8,
                                                   float* __restrict__ Spart) {
    __shared__ unsigned char Bsm[2][TILE_COLS * DIM];   // 2 x 8KB
    const int bid = blockIdx.x;
    const int rt = bid >> 5;   // 32 row tiles of 256 rows
    const int ch = bid & 31;   // 32 column chunks of 256 cols
    const int tid = threadIdx.x;
    const int wave = tid >> 6;
    const int lane = tid & 63;
    const int m16 = lane & 15;
    const int g4 = lane >> 4;

    const int wrow0 = rt * BLK_ROWS + wave * WAVE_ROWS;
    const int col0 = ch * CHUNK_COLS;

    // A fragments: 4 row-frags x 8 k-steps, 8 bytes each (K=32 slice)
    long a[4][8];
#pragma unroll
    for (int rf = 0; rf < 4; ++rf) {
        const long* ap = reinterpret_cast<const long*>(F8 + (size_t)(wrow0 + rf * 16 + m16) * DIM);
#pragma unroll
        for (int ks = 0; ks < 8; ++ks) a[rf][ks] = ap[ks * 4 + g4];
    }

    float sums[4][4];
#pragma unroll
    for (int i = 0; i < 4; ++i)
#pragma unroll
        for (int j = 0; j < 4; ++j) sums[i][j] = 0.0f;

    // stage B tile t into buffer buf (wave-cooperative, 2 x 16B per lane)
    auto stage = [&](int buf, int t) {
#pragma unroll
        for (int i = 0; i < 2; ++i) {
            const int q = (wave * 2 + i) * 64 + lane;      // 16B-chunk id, 0..511
            const int c = q >> 4;                          // local col 0..31
            const int m = q & 15;                          // 16B chunk within col
            const unsigned char* src =
                F8 + (size_t)(col0 + t * TILE_COLS + c) * DIM + ((m ^ (c & 7)) << 4);
            __builtin_amdgcn_global_load_lds((gas_uint*)src,
                                             (las_uint*)(&Bsm[buf][(wave * 2 + i) * 1024]),
                                             16, 0, 0);
        }
    };

    stage(0, 0);
    asm volatile("s_waitcnt vmcnt(0)");
    __syncthreads();

    for (int t = 0; t < NTILE; ++t) {
        const int buf = t & 1;
        if (t + 1 < NTILE) stage(buf ^ 1, t + 1);

        const int cb = col0 + t * TILE_COLS;
        f32x4 acc[4][2];
#pragma unroll
        for (int rf = 0; rf < 4; ++rf)
#pragma unroll
            for (int cf = 0; cf < 2; ++cf) acc[rf][cf] = f32x4{0.f, 0.f, 0.f, 0.f};

#pragma unroll
        for (int ks = 0; ks < 8; ++ks) {
            const int o = ks * 32 + g4 * 8;
            const int c0 = m16;
            const int c1 = 16 + m16;
            const long b0 = *reinterpret_cast<const long*>(&Bsm[buf][c0 * DIM + (o ^ ((c0 & 7) << 4))]);
            const long b1 = *reinterpret_cast<const long*>(&Bsm[buf][c1 * DIM + (o ^ ((c1 & 7) << 4))]);
#pragma unroll
            for (int rf = 0; rf < 4; ++rf) {
                acc[rf][0] = __builtin_amdgcn_mfma_f32_16x16x32_fp8_fp8(a[rf][ks], b0, acc[rf][0], 0, 0, 0);
                acc[rf][1] = __builtin_amdgcn_mfma_f32_16x16x32_fp8_fp8(a[rf][ks], b1, acc[rf][1], 0, 0, 0);
            }
        }

        // epilogue: exp(2*acc), mask diagonal (wave-uniform rare branch), accumulate
        const bool diag = (wrow0 < cb + TILE_COLS) && (cb < wrow0 + WAVE_ROWS);
        if (diag) {
#pragma unroll
            for (int rf = 0; rf < 4; ++rf) {
                const int rbase = wrow0 + rf * 16 + g4 * 4;
#pragma unroll
                for (int cf = 0; cf < 2; ++cf) {
                    const int gcol = cb + cf * 16 + m16;
#pragma unroll
                    for (int j = 0; j < 4; ++j) {
                        const float e = __expf(2.0f * acc[rf][cf][j]);
                        sums[rf][j] += (rbase + j == gcol) ? 0.0f : e;
                    }
                }
            }
        } else {
#pragma unroll
            for (int rf = 0; rf < 4; ++rf)
#pragma unroll
                for (int cf = 0; cf < 2; ++cf)
#pragma unroll
                    for (int j = 0; j < 4; ++j)
                        sums[rf][j] += __expf(2.0f * acc[rf][cf][j]);
        }

        asm volatile("s_waitcnt vmcnt(0)");
        __syncthreads();
    }

    // reduce partials across the 16 lanes holding each row's columns
#pragma unroll
    for (int rf = 0; rf < 4; ++rf) {
#pragma unroll
        for (int j = 0; j < 4; ++j) {
            float s = sums[rf][j];
            s += __shfl_xor(s, 1, 64);
            s += __shfl_xor(s, 2, 64);
            s += __shfl_xor(s, 4, 64);
            s += __shfl_xor(s, 8, 64);
            if (m16 == 0) {
                Spart[(size_t)ch * NTOT + (wrow0 + rf * 16 + g4 * 4 + j)] = s;
            }
        }
    }
}

// K3: combine chunk partials, nll = log(S) - pos_sim, reduce, /N^2
__global__ __launch_bounds__(1024) void k_final(const float* __restrict__ Spart,
                                                const float* __restrict__ pos_sim,
                                                float* __restrict__ out) {
    __shared__ float red[16];
    const int tid = threadIdx.x;
    float local = 0.0f;
    for (int r = tid; r < NTOT; r += 1024) {
        float s = 0.0f;
#pragma unroll
        for (int c = 0; c < NCHUNK; ++c) s += Spart[c * NTOT + r];
        local += logf(s) - pos_sim[r];
    }
    local = wave_reduce_add(local);
    const int wv = tid >> 6;
    if ((tid & 63) == 0) red[wv] = local;
    __syncthreads();
    if (tid == 0) {
        float tot = 0.0f;
#pragma unroll
        for (int w = 0; w < 16; ++w) tot += red[w];
        out[0] = tot / ((float)NTOT * (float)NTOT);
    }
}

extern "C" void kernel_launch(void* const* d_in, const int* in_sizes, int n_in,
                              void* d_out, int out_size, void* d_ws, size_t ws_size,
                              hipStream_t stream) {
    (void)in_sizes; (void)n_in; (void)out_size; (void)ws_size;
    const float* zi = (const float*)d_in[0];
    const float* zj = (const float*)d_in[1];
    float* out = (float*)d_out;

    char* ws = (char*)d_ws;
    unsigned char* F8 = (unsigned char*)ws;                                // 2 MiB fp8 feats
    float* pos_sim = (float*)(ws + (size_t)NTOT * DIM);                    // 32 KiB
    float* Spart = (float*)(ws + (size_t)NTOT * DIM + 65536);              // 1 MiB

    k_norm<<<B_ROWS / WAVES, 256, 0, stream>>>(zi, zj, F8, pos_sim);
    k_simsum<<<(NTOT / BLK_ROWS) * (NTOT / CHUNK_COLS), 256, 0, stream>>>(F8, Spart);
    k_final<<<1, 1024, 0, stream>>>(Spart, pos_sim, out);
}